// Round 1
// baseline (622.749 us; speedup 1.0000x reference)
//
#include <hip/hip_runtime.h>
#include <hip/hip_bf16.h>

// B=2, S=768, H=768, NH=12, D=64, NKEY=9216. Output fp32 [B][S][NH][D].
// Pipeline: transpose-cvt weights -> gemm_q -> gemm_kv (k^T/v^T) ->
//           gemm_kc (kc[key][d]) -> gemm_vct (vc^T[d][key]) -> flash attention.
// All MFMA: v_mfma_f32_16x16x32_bf16, fp32 accumulate.
// LDS rows padded to 144B (odd 16B-chunk stride) -> conflict-free ds_read_b128.

typedef __bf16 bf16_t;
typedef __bf16 bf16x8 __attribute__((ext_vector_type(8)));
typedef float f32x4 __attribute__((ext_vector_type(4)));

#define MFMA16(a, b, c) __builtin_amdgcn_mfma_f32_16x16x32_bf16((a), (b), (c), 0, 0, 0)
#define LOG2E 1.44269504088896340736f
#define SCALE_Q 0.18033688011112042f /* (1/8) * log2(e) */

// ---------------- transpose + convert: Wt[n][k] = (bf16)W[k][n], 768x768 ----
__global__ __launch_bounds__(256) void transpose_cvt(const float* __restrict__ W,
                                                     bf16_t* __restrict__ Wt) {
  __shared__ float t[32][33];
  const int bx = blockIdx.x * 32;  // input row base (k)
  const int by = blockIdx.y * 32;  // input col base (n)
  const int tx = threadIdx.x, ty = threadIdx.y;
#pragma unroll
  for (int i = 0; i < 32; i += 8) t[ty + i][tx] = W[(bx + ty + i) * 768 + by + tx];
  __syncthreads();
#pragma unroll
  for (int i = 0; i < 32; i += 8)
    Wt[(by + ty + i) * 768 + bx + tx] = (bf16_t)t[tx][ty + i];
}

// ---------------- canonical C[M][N] = A[M][K] * B[N][K]^T, bf16 MFMA --------
__device__ __forceinline__ bf16x8 cvt8(const float* __restrict__ src) {
  const float4 a = *(const float4*)src;
  const float4 b = *(const float4*)(src + 4);
  bf16x8 o;
  o[0] = (bf16_t)a.x; o[1] = (bf16_t)a.y; o[2] = (bf16_t)a.z; o[3] = (bf16_t)a.w;
  o[4] = (bf16_t)b.x; o[5] = (bf16_t)b.y; o[6] = (bf16_t)b.z; o[7] = (bf16_t)b.w;
  return o;
}

template <int BM, int BN, bool AF32, bool BF32, typename EPI>
__device__ __forceinline__ void gemm_core(const void* __restrict__ Ap, int lda,
                                          const void* __restrict__ Bp, int ldb,
                                          int K, int m0, int n0, EPI epi) {
  constexpr int MT = BM / 32;   // per-wave m tiles (waves in 2x2)
  constexpr int NT = BN / 32;   // per-wave n tiles
  constexpr int ACH = BM * 8;   // 16B chunks per 64-deep K slab
  constexpr int BCH = BN * 8;
  __shared__ __align__(16) char smem[(BM + BN) * 144];  // 144B padded rows
  char* sA = smem;
  char* sB = smem + BM * 144;

  const int tid = threadIdx.x;
  const int lane = tid & 63;
  const int w = tid >> 6;
  const int l15 = lane & 15, quad = lane >> 4;
  const int wm = (w & 1) * (BM / 2);
  const int wn = (w >> 1) * (BN / 2);

  const f32x4 fzero = {0.f, 0.f, 0.f, 0.f};
  f32x4 acc[MT][NT];
#pragma unroll
  for (int i = 0; i < MT; ++i)
#pragma unroll
    for (int j = 0; j < NT; ++j) acc[i][j] = fzero;

  for (int kk = 0; kk < K; kk += 64) {
#pragma unroll
    for (int c = tid; c < ACH; c += 256) {
      const int r = c >> 3, ch = c & 7;
      if constexpr (AF32) {
        const float* s = (const float*)Ap + (size_t)(m0 + r) * lda + kk + ch * 8;
        *(bf16x8*)(sA + r * 144 + ch * 16) = cvt8(s);
      } else {
        const bf16_t* s = (const bf16_t*)Ap + (size_t)(m0 + r) * lda + kk + ch * 8;
        *(uint4*)(sA + r * 144 + ch * 16) = *(const uint4*)s;
      }
    }
#pragma unroll
    for (int c = tid; c < BCH; c += 256) {
      const int r = c >> 3, ch = c & 7;
      if constexpr (BF32) {
        const float* s = (const float*)Bp + (size_t)(n0 + r) * ldb + kk + ch * 8;
        *(bf16x8*)(sB + r * 144 + ch * 16) = cvt8(s);
      } else {
        const bf16_t* s = (const bf16_t*)Bp + (size_t)(n0 + r) * ldb + kk + ch * 8;
        *(uint4*)(sB + r * 144 + ch * 16) = *(const uint4*)s;
      }
    }
    __syncthreads();
#pragma unroll
    for (int ks = 0; ks < 2; ++ks) {
      bf16x8 af[MT], bfr[NT];
#pragma unroll
      for (int i = 0; i < MT; ++i)
        af[i] = *(const bf16x8*)(sA + (wm + i * 16 + l15) * 144 + ks * 64 + quad * 16);
#pragma unroll
      for (int j = 0; j < NT; ++j)
        bfr[j] = *(const bf16x8*)(sB + (wn + j * 16 + l15) * 144 + ks * 64 + quad * 16);
#pragma unroll
      for (int i = 0; i < MT; ++i)
#pragma unroll
        for (int j = 0; j < NT; ++j) acc[i][j] = MFMA16(af[i], bfr[j], acc[i][j]);
    }
    __syncthreads();
  }
#pragma unroll
  for (int i = 0; i < MT; ++i)
#pragma unroll
    for (int j = 0; j < NT; ++j)
#pragma unroll
      for (int p = 0; p < 4; ++p)
        epi(m0 + wm + i * 16 + quad * 4 + p, n0 + wn + j * 16 + l15, acc[i][j][p]);
}

// q[b,h,s,d] = (hid @ Wq + bq) * (0.125*log2e), bf16
__global__ __launch_bounds__(256) void gemm_q(const float* __restrict__ hid,
                                              const bf16_t* __restrict__ wqT,
                                              const float* __restrict__ bq,
                                              bf16_t* __restrict__ q) {
  const int m0 = blockIdx.x * 128, n0 = blockIdx.y * 128;
  auto epi = [=](int m, int n, float v) {
    const int b = m / 768, s = m - b * 768;
    const int h = n >> 6, d = n & 63;
    q[((size_t)((b * 12 + h) * 768 + s) << 6) + d] = (bf16_t)((v + bq[n]) * SCALE_Q);
  };
  gemm_core<128, 128, true, false>(hid, 768, wqT, 768, 768, m0, n0, epi);
}

// ktvt[(h,d)][(b,s)]: rows 0..767 = k^T (+bk), rows 768..1535 = v^T (+bv)
__global__ __launch_bounds__(256) void gemm_kv(const bf16_t* __restrict__ wkvT,
                                               const float* __restrict__ hid,
                                               const float* __restrict__ bk,
                                               const float* __restrict__ bv,
                                               bf16_t* __restrict__ ktvt) {
  const int m0 = blockIdx.x * 128, n0 = blockIdx.y * 128;
  auto epi = [=](int m, int n, float v) {
    const float bias = (m < 768) ? bk[m] : bv[m - 768];
    ktvt[(size_t)m * 1536 + n] = (bf16_t)(v + bias);
  };
  gemm_core<128, 128, false, true>(wkvT, 768, hid, 768, 768, m0, n0, epi);
}

// kc[b][h*768+kout][d] = memk[h] @ k[b,h]   (A fp32 staged->bf16)
__global__ __launch_bounds__(256) void gemm_kc(const float* __restrict__ memk,
                                               const bf16_t* __restrict__ ktvt,
                                               bf16_t* __restrict__ kc) {
  const int z = blockIdx.z, b = z / 12, h = z - (z / 12) * 12;
  const int m0 = blockIdx.x * 128;
  const float* A = memk + (size_t)h * 589824;
  const bf16_t* B = ktvt + (size_t)(h * 64) * 1536 + b * 768;
  bf16_t* outp = kc + (size_t)b * 589824 + (size_t)h * 768 * 64;
  auto epi = [=](int m, int n, float v) { outp[((size_t)m << 6) + n] = (bf16_t)v; };
  gemm_core<128, 64, true, false>(A, 768, B, 1536, 768, m0, 0, epi);
}

// vct[b][d][h*768+kout] = (memv[h] @ v[b,h])^T  via  v^T-slice . memv[h]^T
__global__ __launch_bounds__(256) void gemm_vct(const bf16_t* __restrict__ ktvt,
                                                const float* __restrict__ memv,
                                                bf16_t* __restrict__ vct) {
  const int z = blockIdx.z, b = z / 12, h = z - (z / 12) * 12;
  const int n0 = blockIdx.y * 128;
  const bf16_t* A = ktvt + (size_t)(768 + h * 64) * 1536 + b * 768;
  const float* B = memv + (size_t)h * 589824;
  bf16_t* outp = vct + (size_t)b * 589824 + h * 768;
  auto epi = [=](int m, int n, float v) { outp[(size_t)m * 9216 + n] = (bf16_t)v; };
  gemm_core<64, 128, false, true>(A, 1536, B, 768, 768, 0, n0, epi);
}

// ---------------- flash attention over 9216 keys, KT=64, Qtile=64 ----------
__global__ __launch_bounds__(256) void flash_attn(const bf16_t* __restrict__ q,
                                                  const bf16_t* __restrict__ kc,
                                                  const bf16_t* __restrict__ vct,
                                                  const float* __restrict__ mask,
                                                  const float* __restrict__ gate,
                                                  float* __restrict__ out) {
  const int qt = blockIdx.x, h = blockIdx.y, b = blockIdx.z;
  const int tid = threadIdx.x;
  const int w = tid >> 6, lane = tid & 63, l15 = lane & 15, quad = lane >> 4;

  __shared__ __align__(16) bf16_t kc_s[64 * 72];     // [key][d], 144B rows
  __shared__ __align__(16) bf16_t vt_s[64 * 72];     // [d][key], 144B rows
  __shared__ __align__(16) bf16_t p_s[4][16 * 72];   // per-wave P [row][key]
  __shared__ float mask_s[64];

  // Q fragments (A-operand, rows = wave's 16 q-rows), pre-scaled in gemm_q
  const bf16_t* qrow =
      q + ((size_t)((b * 12 + h) * 768 + qt * 64 + w * 16 + l15) << 6);
  const bf16x8 qa0 = *(const bf16x8*)(qrow + quad * 8);
  const bf16x8 qa1 = *(const bf16x8*)(qrow + 32 + quad * 8);

  const bf16_t* kcb = kc + (size_t)b * 589824;
  const bf16_t* vtb = vct + (size_t)b * 589824;
  const float* mkb = mask + b * 9216;

  const f32x4 fzero = {0.f, 0.f, 0.f, 0.f};
  float m_i[4] = {-1e30f, -1e30f, -1e30f, -1e30f};
  float l_i[4] = {0.f, 0.f, 0.f, 0.f};
  f32x4 acc[4];
#pragma unroll
  for (int nt = 0; nt < 4; ++nt) acc[nt] = fzero;

  bf16_t* psw = p_s[w];

  for (int t = 0; t < 144; ++t) {
    const int k0 = t * 64;
#pragma unroll
    for (int c = tid; c < 512; c += 256) {  // stage kc tile + vt tile (16KB)
      const int r = c >> 3, ch = c & 7;
      *(uint4*)((char*)kc_s + r * 144 + ch * 16) =
          *(const uint4*)(kcb + ((size_t)(k0 + r) << 6) + ch * 8);
      *(uint4*)((char*)vt_s + r * 144 + ch * 16) =
          *(const uint4*)(vtb + (size_t)r * 9216 + k0 + ch * 8);
    }
    if (tid < 16) {
      const float4 mv = *(const float4*)(mkb + k0 + tid * 4);
      mask_s[tid * 4 + 0] = mv.x * LOG2E;
      mask_s[tid * 4 + 1] = mv.y * LOG2E;
      mask_s[tid * 4 + 2] = mv.z * LOG2E;
      mask_s[tid * 4 + 3] = mv.w * LOG2E;
    }
    __syncthreads();

    // S = Q.Kc^T (base-2 logits), + mask
    f32x4 s[4];
#pragma unroll
    for (int nt = 0; nt < 4; ++nt) {
      const char* kp = (const char*)kc_s + (nt * 16 + l15) * 144 + quad * 16;
      const bf16x8 b0 = *(const bf16x8*)kp;
      const bf16x8 b1 = *(const bf16x8*)(kp + 64);
      f32x4 z = fzero;
      z = MFMA16(qa0, b0, z);
      z = MFMA16(qa1, b1, z);
      const float mk = mask_s[nt * 16 + l15];
#pragma unroll
      for (int p = 0; p < 4; ++p) s[nt][p] = z[p] + mk;
    }

    // online softmax: row max over 64 keys (4 regs + 16-lane shuffle)
    float alpha[4], rsum[4];
#pragma unroll
    for (int p = 0; p < 4; ++p) {
      float v = fmaxf(fmaxf(s[0][p], s[1][p]), fmaxf(s[2][p], s[3][p]));
#pragma unroll
      for (int off = 1; off < 16; off <<= 1) v = fmaxf(v, __shfl_xor(v, off));
      const float mn = fmaxf(m_i[p], v);
      alpha[p] = exp2f(m_i[p] - mn);
      m_i[p] = mn;
      rsum[p] = 0.f;
    }
#pragma unroll
    for (int nt = 0; nt < 4; ++nt)
#pragma unroll
      for (int p = 0; p < 4; ++p) {
        const float pv = exp2f(s[nt][p] - m_i[p]);
        rsum[p] += pv;
        // C-layout (row=quad*4+p, col=nt*16+l15) -> LDS row-major [row][key]
        psw[(quad * 4 + p) * 72 + nt * 16 + l15] = (bf16_t)pv;
      }
#pragma unroll
    for (int p = 0; p < 4; ++p) {
      float v = rsum[p];
#pragma unroll
      for (int off = 1; off < 16; off <<= 1) v += __shfl_xor(v, off);
      l_i[p] = l_i[p] * alpha[p] + v;
    }
#pragma unroll
    for (int nt = 0; nt < 4; ++nt)
#pragma unroll
      for (int p = 0; p < 4; ++p) acc[nt][p] *= alpha[p];

    // ctx += P.V  (A from P LDS, B from transposed-V LDS)
    const bf16x8 pa0 = *(const bf16x8*)((char*)psw + l15 * 144 + quad * 16);
    const bf16x8 pa1 = *(const bf16x8*)((char*)psw + l15 * 144 + 64 + quad * 16);
#pragma unroll
    for (int nt = 0; nt < 4; ++nt) {
      const char* vp = (const char*)vt_s + (nt * 16 + l15) * 144 + quad * 16;
      const bf16x8 b0 = *(const bf16x8*)vp;
      const bf16x8 b1 = *(const bf16x8*)(vp + 64);
      acc[nt] = MFMA16(pa0, b0, acc[nt]);
      acc[nt] = MFMA16(pa1, b1, acc[nt]);
    }
    __syncthreads();
  }

  // epilogue: normalize, sigmoid gate, write [b][s][h][d] fp32
  const float g = 1.f / (1.f + expf(-gate[h]));
  float inv[4];
#pragma unroll
  for (int p = 0; p < 4; ++p) inv[p] = g / l_i[p];
  const int sbase = qt * 64 + w * 16 + quad * 4;
#pragma unroll
  for (int nt = 0; nt < 4; ++nt)
#pragma unroll
    for (int p = 0; p < 4; ++p)
      out[((size_t)((b * 768 + sbase + p) * 12 + h) << 6) + nt * 16 + l15] =
          acc[nt][p] * inv[p];
}

extern "C" void kernel_launch(void* const* d_in, const int* in_sizes, int n_in,
                              void* d_out, int out_size, void* d_ws, size_t ws_size,
                              hipStream_t stream) {
  const float* hid  = (const float*)d_in[0];
  const float* mask = (const float*)d_in[1];
  const float* Wq   = (const float*)d_in[2];
  const float* bq   = (const float*)d_in[3];
  const float* Wk   = (const float*)d_in[4];
  const float* bk   = (const float*)d_in[5];
  const float* Wv   = (const float*)d_in[6];
  const float* bv   = (const float*)d_in[7];
  const float* gate = (const float*)d_in[8];
  const float* memk = (const float*)d_in[9];
  const float* memv = (const float*)d_in[10];
  float* out = (float*)d_out;

  // workspace layout (15.3 MB total)
  char* ws = (char*)d_ws;
  bf16_t* wqkvT = (bf16_t*)(ws);             // [2304][768] bf16: Wq^T,Wk^T,Wv^T
  bf16_t* qb    = (bf16_t*)(ws + 3538944);   // q [2][12][768][64] bf16
  bf16_t* ktvt  = (bf16_t*)(ws + 5898240);   // [1536][1536] bf16: k^T then v^T
  bf16_t* kcw   = (bf16_t*)(ws + 10616832);  // kc [2][9216][64] bf16
  bf16_t* vct   = (bf16_t*)(ws + 12976128);  // vc^T [2][64][9216] bf16

  const dim3 tb(32, 8);
  transpose_cvt<<<dim3(24, 24), tb, 0, stream>>>(Wq, wqkvT);
  transpose_cvt<<<dim3(24, 24), tb, 0, stream>>>(Wk, wqkvT + 589824);
  transpose_cvt<<<dim3(24, 24), tb, 0, stream>>>(Wv, wqkvT + 1179648);
  gemm_q<<<dim3(12, 6), 256, 0, stream>>>(hid, wqkvT, bq, qb);
  gemm_kv<<<dim3(12, 12), 256, 0, stream>>>(wqkvT + 589824, hid, bk, bv, ktvt);
  gemm_kc<<<dim3(6, 1, 24), 256, 0, stream>>>(memk, ktvt, kcw);
  gemm_vct<<<dim3(1, 6, 24), 256, 0, stream>>>(ktvt, memv, vct);
  flash_attn<<<dim3(12, 12, 2), 256, 0, stream>>>(qb, kcw, vct, mask, gate, out);
}

// Round 2
// 371.558 us; speedup vs baseline: 1.6760x; 1.6760x over previous
//
#include <hip/hip_runtime.h>
#include <hip/hip_bf16.h>

// B=2, S=768, H=768, NH=12, D=64, NKEY=9216. Output fp32 [B][S][NH][D].
// Round 2: flash-decoding split-K (8 chunks -> 2304 blocks) + merged GEMM
// launches. All MFMA: v_mfma_f32_16x16x32_bf16, fp32 accumulate.
// LDS rows padded to 144B (odd 16B-chunk stride) -> conflict-free ds_read_b128.

typedef __bf16 bf16_t;
typedef __bf16 bf16x8 __attribute__((ext_vector_type(8)));
typedef float f32x4 __attribute__((ext_vector_type(4)));

#define MFMA16(a, b, c) __builtin_amdgcn_mfma_f32_16x16x32_bf16((a), (b), (c), 0, 0, 0)
#define LOG2E 1.44269504088896340736f
#define SCALE_Q 0.18033688011112042f /* (1/8) * log2(e) */
#define NSPLIT 8
#define KCHUNK 1152 /* 9216/8, 18 iters of 64 */

// ---------------- transpose + convert: Wt[n][k] = (bf16)W[k][n], 768x768 ----
// z selects Wq/Wk/Wv.
__global__ __launch_bounds__(256) void transpose_cvt3(const float* __restrict__ Wq,
                                                      const float* __restrict__ Wk,
                                                      const float* __restrict__ Wv,
                                                      bf16_t* __restrict__ Wt) {
  __shared__ float t[32][33];
  const float* W = (blockIdx.z == 0) ? Wq : (blockIdx.z == 1) ? Wk : Wv;
  bf16_t* o = Wt + (size_t)blockIdx.z * 589824;
  const int bx = blockIdx.x * 32;  // input row base (k)
  const int by = blockIdx.y * 32;  // input col base (n)
  const int tx = threadIdx.x, ty = threadIdx.y;
#pragma unroll
  for (int i = 0; i < 32; i += 8) t[ty + i][tx] = W[(bx + ty + i) * 768 + by + tx];
  __syncthreads();
#pragma unroll
  for (int i = 0; i < 32; i += 8)
    o[(by + ty + i) * 768 + bx + tx] = (bf16_t)t[tx][ty + i];
}

// ---------------- canonical C[M][N] = A[M][K] * B[N][K]^T, bf16 MFMA --------
__device__ __forceinline__ bf16x8 cvt8(const float* __restrict__ src) {
  const float4 a = *(const float4*)src;
  const float4 b = *(const float4*)(src + 4);
  bf16x8 o;
  o[0] = (bf16_t)a.x; o[1] = (bf16_t)a.y; o[2] = (bf16_t)a.z; o[3] = (bf16_t)a.w;
  o[4] = (bf16_t)b.x; o[5] = (bf16_t)b.y; o[6] = (bf16_t)b.z; o[7] = (bf16_t)b.w;
  return o;
}

template <int BM, int BN, bool AF32, bool BF32, typename EPI>
__device__ __forceinline__ void gemm_core(char* __restrict__ smem,
                                          const void* __restrict__ Ap, int lda,
                                          const void* __restrict__ Bp, int ldb,
                                          int K, int m0, int n0, EPI epi) {
  constexpr int MT = BM / 32;   // per-wave m tiles (waves in 2x2)
  constexpr int NT = BN / 32;   // per-wave n tiles
  constexpr int ACH = BM * 8;   // 16B chunks per 64-deep K slab
  constexpr int BCH = BN * 8;
  char* sA = smem;
  char* sB = smem + BM * 144;

  const int tid = threadIdx.x;
  const int lane = tid & 63;
  const int w = tid >> 6;
  const int l15 = lane & 15, quad = lane >> 4;
  const int wm = (w & 1) * (BM / 2);
  const int wn = (w >> 1) * (BN / 2);

  const f32x4 fzero = {0.f, 0.f, 0.f, 0.f};
  f32x4 acc[MT][NT];
#pragma unroll
  for (int i = 0; i < MT; ++i)
#pragma unroll
    for (int j = 0; j < NT; ++j) acc[i][j] = fzero;

  for (int kk = 0; kk < K; kk += 64) {
#pragma unroll
    for (int c = tid; c < ACH; c += 256) {
      const int r = c >> 3, ch = c & 7;
      if constexpr (AF32) {
        const float* s = (const float*)Ap + (size_t)(m0 + r) * lda + kk + ch * 8;
        *(bf16x8*)(sA + r * 144 + ch * 16) = cvt8(s);
      } else {
        const bf16_t* s = (const bf16_t*)Ap + (size_t)(m0 + r) * lda + kk + ch * 8;
        *(uint4*)(sA + r * 144 + ch * 16) = *(const uint4*)s;
      }
    }
#pragma unroll
    for (int c = tid; c < BCH; c += 256) {
      const int r = c >> 3, ch = c & 7;
      if constexpr (BF32) {
        const float* s = (const float*)Bp + (size_t)(n0 + r) * ldb + kk + ch * 8;
        *(bf16x8*)(sB + r * 144 + ch * 16) = cvt8(s);
      } else {
        const bf16_t* s = (const bf16_t*)Bp + (size_t)(n0 + r) * ldb + kk + ch * 8;
        *(uint4*)(sB + r * 144 + ch * 16) = *(const uint4*)s;
      }
    }
    __syncthreads();
#pragma unroll
    for (int ks = 0; ks < 2; ++ks) {
      bf16x8 af[MT], bfr[NT];
#pragma unroll
      for (int i = 0; i < MT; ++i)
        af[i] = *(const bf16x8*)(sA + (wm + i * 16 + l15) * 144 + ks * 64 + quad * 16);
#pragma unroll
      for (int j = 0; j < NT; ++j)
        bfr[j] = *(const bf16x8*)(sB + (wn + j * 16 + l15) * 144 + ks * 64 + quad * 16);
#pragma unroll
      for (int i = 0; i < MT; ++i)
#pragma unroll
        for (int j = 0; j < NT; ++j) acc[i][j] = MFMA16(af[i], bfr[j], acc[i][j]);
    }
    __syncthreads();
  }
#pragma unroll
  for (int i = 0; i < MT; ++i)
#pragma unroll
    for (int j = 0; j < NT; ++j)
#pragma unroll
      for (int p = 0; p < 4; ++p)
        epi(m0 + wm + i * 16 + quad * 4 + p, n0 + wn + j * 16 + l15, acc[i][j][p]);
}

// Merged QKV projections.
//  y<6 : q[b,h,s,d] = (hid @ Wq + bq) * SCALE_Q              (bf16 out)
//  y>=6: ktvt[(h,d)][(b,s)] rows 0..767 k^T(+bk), 768..1535 v^T(+bv)
__global__ __launch_bounds__(256) void gemm_qkv(const float* __restrict__ hid,
                                                const bf16_t* __restrict__ wT,
                                                const float* __restrict__ bq,
                                                const float* __restrict__ bk,
                                                const float* __restrict__ bv,
                                                bf16_t* __restrict__ q,
                                                bf16_t* __restrict__ ktvt) {
  __shared__ __align__(16) char smem[(128 + 128) * 144];
  if (blockIdx.y < 6) {
    const int m0 = blockIdx.x * 128, n0 = blockIdx.y * 128;
    auto epi = [=](int m, int n, float v) {
      const int b = m / 768, s = m - b * 768;
      const int h = n >> 6, d = n & 63;
      q[((size_t)((b * 12 + h) * 768 + s) << 6) + d] = (bf16_t)((v + bq[n]) * SCALE_Q);
    };
    gemm_core<128, 128, true, false>(smem, hid, 768, wT, 768, 768, m0, n0, epi);
  } else {
    const int m0 = blockIdx.x * 128, n0 = (blockIdx.y - 6) * 128;
    auto epi = [=](int m, int n, float v) {
      const float bias = (m < 768) ? bk[m] : bv[m - 768];
      ktvt[(size_t)m * 1536 + n] = (bf16_t)(v + bias);
    };
    gemm_core<128, 128, false, true>(smem, wT + 589824, 768, hid, 768, 768, m0, n0, epi);
  }
}

// Merged memory GEMMs.
//  y=0: kc[b][h*768+kout][d] = memk[h] @ k[b,h]
//  y=1: vct[b][d][h*768+kout] = (memv[h] @ v[b,h])^T
__global__ __launch_bounds__(256) void gemm_mem(const float* __restrict__ memk,
                                                const float* __restrict__ memv,
                                                const bf16_t* __restrict__ ktvt,
                                                bf16_t* __restrict__ kc,
                                                bf16_t* __restrict__ vct) {
  __shared__ __align__(16) char smem[(128 + 64) * 144];
  const int z = blockIdx.z, b = z / 12, h = z - (z / 12) * 12;
  if (blockIdx.y == 0) {
    const int m0 = blockIdx.x * 128;
    const float* A = memk + (size_t)h * 589824;
    const bf16_t* B = ktvt + (size_t)(h * 64) * 1536 + b * 768;
    bf16_t* outp = kc + (size_t)b * 589824 + (size_t)h * 768 * 64;
    auto epi = [=](int m, int n, float v) { outp[((size_t)m << 6) + n] = (bf16_t)v; };
    gemm_core<128, 64, true, false>(smem, A, 768, B, 1536, 768, m0, 0, epi);
  } else {
    const int n0 = blockIdx.x * 128;
    const bf16_t* A = ktvt + (size_t)(768 + h * 64) * 1536 + b * 768;
    const float* B = memv + (size_t)h * 589824;
    bf16_t* outp = vct + (size_t)b * 589824 + h * 768;
    auto epi = [=](int m, int n, float v) { outp[(size_t)m * 9216 + n] = (bf16_t)v; };
    gemm_core<64, 128, false, true>(smem, A, 1536, B, 768, 768, 0, n0, epi);
  }
}

// ---------------- flash attention, split-K over 8 chunks of 1152 keys ------
__global__ __launch_bounds__(256) void flash_attn_split(
    const bf16_t* __restrict__ q, const bf16_t* __restrict__ kc,
    const bf16_t* __restrict__ vct, const float* __restrict__ mask,
    float* __restrict__ part_acc, float* __restrict__ part_ml) {
  const int qt = blockIdx.x, h = blockIdx.y;
  const int z = blockIdx.z, b = z >> 3, c = z & 7;
  const int tid = threadIdx.x;
  const int w = tid >> 6, lane = tid & 63, l15 = lane & 15, quad = lane >> 4;

  __shared__ __align__(16) bf16_t kc_s[64 * 72];     // [key][d], 144B rows
  __shared__ __align__(16) bf16_t vt_s[64 * 72];     // [d][key], 144B rows
  __shared__ __align__(16) bf16_t p_s[4][16 * 72];   // per-wave P [row][key]
  __shared__ float mask_s[64];

  // Q fragments (A-operand, rows = wave's 16 q-rows), pre-scaled in gemm_q
  const bf16_t* qrow =
      q + ((size_t)((b * 12 + h) * 768 + qt * 64 + w * 16 + l15) << 6);
  const bf16x8 qa0 = *(const bf16x8*)(qrow + quad * 8);
  const bf16x8 qa1 = *(const bf16x8*)(qrow + 32 + quad * 8);

  const bf16_t* kcb = kc + (size_t)b * 589824;
  const bf16_t* vtb = vct + (size_t)b * 589824;
  const float* mkb = mask + b * 9216;

  const f32x4 fzero = {0.f, 0.f, 0.f, 0.f};
  float m_i[4] = {-1e30f, -1e30f, -1e30f, -1e30f};
  float l_i[4] = {0.f, 0.f, 0.f, 0.f};
  f32x4 acc[4];
#pragma unroll
  for (int nt = 0; nt < 4; ++nt) acc[nt] = fzero;

  bf16_t* psw = p_s[w];

  for (int t = 0; t < KCHUNK / 64; ++t) {
    const int k0 = c * KCHUNK + t * 64;
#pragma unroll
    for (int cc = tid; cc < 512; cc += 256) {  // stage kc tile + vt tile (16KB)
      const int r = cc >> 3, ch = cc & 7;
      *(uint4*)((char*)kc_s + r * 144 + ch * 16) =
          *(const uint4*)(kcb + ((size_t)(k0 + r) << 6) + ch * 8);
      *(uint4*)((char*)vt_s + r * 144 + ch * 16) =
          *(const uint4*)(vtb + (size_t)r * 9216 + k0 + ch * 8);
    }
    if (tid < 16) {
      const float4 mv = *(const float4*)(mkb + k0 + tid * 4);
      mask_s[tid * 4 + 0] = mv.x * LOG2E;
      mask_s[tid * 4 + 1] = mv.y * LOG2E;
      mask_s[tid * 4 + 2] = mv.z * LOG2E;
      mask_s[tid * 4 + 3] = mv.w * LOG2E;
    }
    __syncthreads();

    // S = Q.Kc^T (base-2 logits), + mask
    f32x4 s[4];
#pragma unroll
    for (int nt = 0; nt < 4; ++nt) {
      const char* kp = (const char*)kc_s + (nt * 16 + l15) * 144 + quad * 16;
      const bf16x8 b0 = *(const bf16x8*)kp;
      const bf16x8 b1 = *(const bf16x8*)(kp + 64);
      f32x4 zacc = fzero;
      zacc = MFMA16(qa0, b0, zacc);
      zacc = MFMA16(qa1, b1, zacc);
      const float mk = mask_s[nt * 16 + l15];
#pragma unroll
      for (int p = 0; p < 4; ++p) s[nt][p] = zacc[p] + mk;
    }

    // online softmax: row max over 64 keys (4 regs + 16-lane shuffle)
    float alpha[4], rsum[4];
#pragma unroll
    for (int p = 0; p < 4; ++p) {
      float v = fmaxf(fmaxf(s[0][p], s[1][p]), fmaxf(s[2][p], s[3][p]));
#pragma unroll
      for (int off = 1; off < 16; off <<= 1) v = fmaxf(v, __shfl_xor(v, off));
      const float mn = fmaxf(m_i[p], v);
      alpha[p] = exp2f(m_i[p] - mn);
      m_i[p] = mn;
      rsum[p] = 0.f;
    }
#pragma unroll
    for (int nt = 0; nt < 4; ++nt)
#pragma unroll
      for (int p = 0; p < 4; ++p) {
        const float pv = exp2f(s[nt][p] - m_i[p]);
        rsum[p] += pv;
        // C-layout (row=quad*4+p, col=nt*16+l15) -> LDS row-major [row][key]
        psw[(quad * 4 + p) * 72 + nt * 16 + l15] = (bf16_t)pv;
      }
#pragma unroll
    for (int p = 0; p < 4; ++p) {
      float v = rsum[p];
#pragma unroll
      for (int off = 1; off < 16; off <<= 1) v += __shfl_xor(v, off);
      l_i[p] = l_i[p] * alpha[p] + v;
    }
#pragma unroll
    for (int nt = 0; nt < 4; ++nt)
#pragma unroll
      for (int p = 0; p < 4; ++p) acc[nt][p] *= alpha[p];

    // ctx += P.V  (A from P LDS, B from transposed-V LDS)
    const bf16x8 pa0 = *(const bf16x8*)((char*)psw + l15 * 144 + quad * 16);
    const bf16x8 pa1 = *(const bf16x8*)((char*)psw + l15 * 144 + 64 + quad * 16);
#pragma unroll
    for (int nt = 0; nt < 4; ++nt) {
      const char* vp = (const char*)vt_s + (nt * 16 + l15) * 144 + quad * 16;
      const bf16x8 b0 = *(const bf16x8*)vp;
      const bf16x8 b1 = *(const bf16x8*)(vp + 64);
      acc[nt] = MFMA16(pa0, b0, acc[nt]);
      acc[nt] = MFMA16(pa1, b1, acc[nt]);
    }
    __syncthreads();
  }

  // write unnormalized partials for the combine kernel
  const int pidx = ((b * 12 + h) * 12 + qt) * NSPLIT + c;
  float* pacc = part_acc + (size_t)pidx * 4096;
#pragma unroll
  for (int nt = 0; nt < 4; ++nt)
#pragma unroll
    for (int p = 0; p < 4; ++p)
      pacc[(w * 16 + quad * 4 + p) * 64 + nt * 16 + l15] = acc[nt][p];
  if (l15 == 0) {
#pragma unroll
    for (int p = 0; p < 4; ++p) {
      part_ml[(size_t)pidx * 128 + w * 16 + quad * 4 + p] = m_i[p];
      part_ml[(size_t)pidx * 128 + 64 + w * 16 + quad * 4 + p] = l_i[p];
    }
  }
}

// ---------------- combine split-K partials, normalize, gate, write out -----
__global__ __launch_bounds__(256) void flash_combine(
    const float* __restrict__ part_acc, const float* __restrict__ part_ml,
    const float* __restrict__ gate, float* __restrict__ out) {
  const int qt = blockIdx.x, h = blockIdx.y, b = blockIdx.z;
  const int tid = threadIdx.x;
  const int row = tid >> 2, dseg = tid & 3;  // row 0..63, 16 d-elems per thread
  const int base = ((b * 12 + h) * 12 + qt) * NSPLIT;

  float mv[NSPLIT], lv[NSPLIT], m_g = -1e30f;
#pragma unroll
  for (int ci = 0; ci < NSPLIT; ++ci) {
    mv[ci] = part_ml[(size_t)(base + ci) * 128 + row];
    lv[ci] = part_ml[(size_t)(base + ci) * 128 + 64 + row];
    m_g = fmaxf(m_g, mv[ci]);
  }
  float L = 0.f, wc[NSPLIT];
#pragma unroll
  for (int ci = 0; ci < NSPLIT; ++ci) {
    wc[ci] = exp2f(mv[ci] - m_g);
    L += lv[ci] * wc[ci];
  }
  f32x4 accv[4] = {};
#pragma unroll
  for (int ci = 0; ci < NSPLIT; ++ci) {
    const float* p = part_acc + (size_t)(base + ci) * 4096 + row * 64 + dseg * 16;
#pragma unroll
    for (int j = 0; j < 4; ++j) {
      const float4 v = *(const float4*)(p + j * 4);
      accv[j][0] += wc[ci] * v.x;
      accv[j][1] += wc[ci] * v.y;
      accv[j][2] += wc[ci] * v.z;
      accv[j][3] += wc[ci] * v.w;
    }
  }
  const float g = 1.f / (1.f + expf(-gate[h]));
  const float sc = g / L;
  float* op = out + ((size_t)((b * 768 + qt * 64 + row) * 12 + h) << 6) + dseg * 16;
#pragma unroll
  for (int j = 0; j < 4; ++j) {
    float4 o;
    o.x = accv[j][0] * sc;
    o.y = accv[j][1] * sc;
    o.z = accv[j][2] * sc;
    o.w = accv[j][3] * sc;
    *(float4*)(op + j * 4) = o;
  }
}

extern "C" void kernel_launch(void* const* d_in, const int* in_sizes, int n_in,
                              void* d_out, int out_size, void* d_ws, size_t ws_size,
                              hipStream_t stream) {
  const float* hid  = (const float*)d_in[0];
  const float* mask = (const float*)d_in[1];
  const float* Wq   = (const float*)d_in[2];
  const float* bq   = (const float*)d_in[3];
  const float* Wk   = (const float*)d_in[4];
  const float* bk   = (const float*)d_in[5];
  const float* Wv   = (const float*)d_in[6];
  const float* bv   = (const float*)d_in[7];
  const float* gate = (const float*)d_in[8];
  const float* memk = (const float*)d_in[9];
  const float* memv = (const float*)d_in[10];
  float* out = (float*)d_out;

  // workspace layout (54.3 MB total)
  char* ws = (char*)d_ws;
  bf16_t* wqkvT    = (bf16_t*)(ws);             // [2304][768] bf16
  bf16_t* qb       = (bf16_t*)(ws + 3538944);   // q [2][12][768][64] bf16
  bf16_t* ktvt     = (bf16_t*)(ws + 5898240);   // [1536][1536] bf16
  bf16_t* kcw      = (bf16_t*)(ws + 10616832);  // kc [2][9216][64] bf16
  bf16_t* vct      = (bf16_t*)(ws + 12976128);  // vc^T [2][64][9216] bf16
  float*  part_acc = (float*)(ws + 15335424);   // [2304][64][64] fp32
  float*  part_ml  = (float*)(ws + 53084160);   // [2304][2][64] fp32

  transpose_cvt3<<<dim3(24, 24, 3), dim3(32, 8), 0, stream>>>(Wq, Wk, Wv, wqkvT);
  gemm_qkv<<<dim3(12, 18), 256, 0, stream>>>(hid, wqkvT, bq, bk, bv, qb, ktvt);
  gemm_mem<<<dim3(6, 2, 24), 256, 0, stream>>>(memk, memv, ktvt, kcw, vct);
  flash_attn_split<<<dim3(12, 12, 2 * NSPLIT), 256, 0, stream>>>(qb, kcw, vct, mask,
                                                                 part_acc, part_ml);
  flash_combine<<<dim3(12, 12, 2), 256, 0, stream>>>(part_acc, part_ml, gate, out);
}